// Round 7
// baseline (34058.817 us; speedup 1.0000x reference)
//
#include <hip/hip_runtime.h>

#define B_ 128
#define T_ 1024
#define H_ 400
#define G4H 1600
#define NBLK 256
#define NTHR 512
#define G0N 86
#define G1N 169
#define SL (B_ * H_)   // halfs per h slot
#define SCOPE __HIP_MEMORY_SCOPE_AGENT

typedef float f32x4 __attribute__((ext_vector_type(4)));
typedef _Float16 h2 __attribute__((ext_vector_type(2)));
typedef _Float16 h4 __attribute__((ext_vector_type(4)));
union V4 { f32x4 f; h2 h[4]; };

// LDS layout (bytes): one 128x256-half staging buf + fp16 weights + fp32 gates/cell
#define SWOFF 65536
#define SGS   85312
#define SCST  95552
#define SMEMB 98112

__device__ __forceinline__ float sigmf(float x) { return 1.0f / (1.0f + __expf(-x)); }

// plain cached 16B load (L1+L2). For h-state this is valid ONLY after this wave's
// acquire (buffer_inv) this step; for immutable inputs always valid.
__device__ __forceinline__ void pload4(f32x4& r, const void* p) {
  asm volatile("global_load_dwordx4 %0, %1, off" : "=v"(r) : "v"(p) : "memory");
}
// drain ALL outstanding vmem (count-independent -> immune to compiler-inserted vmem/spills)
__device__ __forceinline__ void vwait0() {
  asm volatile("s_waitcnt vmcnt(0)" ::: "memory");
  __builtin_amdgcn_sched_barrier(0);   // rule #18
}
// agent-scope acquire: emits buffer_inv (drop stale L1 + XCD-L2 lines). Every wave
// executes this after its step's flag-polls, BEFORE plain h-loads. Value unused.
__device__ __forceinline__ void aacq(const int* p) {
  (void)__hip_atomic_load(p, __ATOMIC_ACQUIRE, SCOPE);
  __builtin_amdgcn_sched_barrier(0);
}

__device__ __forceinline__ float dot2f(h2 a, h2 b, float c) {
#if __has_builtin(__builtin_amdgcn_fdot2)
  return __builtin_amdgcn_fdot2(a, b, c, false);
#else
  return fmaf((float)a[0], (float)b[0], fmaf((float)a[1], (float)b[1], c));
#endif
}

// wave-parallel poll of 8 per-group sub-counters (lane&7 -> group); whole wave calls.
// sc0 sc1 loads: LLC-truth, immune to cache staleness.
__device__ __forceinline__ void poll8(const int* p, int tgt) {
  for (;;) {
    int v;
    asm volatile("global_load_dword %0, %1, off sc0 sc1\n\ts_waitcnt vmcnt(0)"
                 : "=v"(v) : "v"(p) : "memory");
    if (__all(v >= tgt)) return;
    __builtin_amdgcn_s_sleep(1);
  }
}
__device__ __forceinline__ void publish(int* f) {
  asm volatile("s_waitcnt vmcnt(0)" ::: "memory");   // drain this thread's h-stores (LLC)
  __syncthreads();                                    // all threads drained
  if (threadIdx.x == 0) __hip_atomic_fetch_add(f, 1, __ATOMIC_RELAXED, SCOPE);
}
// h-store: sc0 sc1 -> lands in LLC, bypasses L2 (no dirty L2 lines can ever exist)
__device__ __forceinline__ void cstoreh(_Float16* p, float v) {
  union { _Float16 h; unsigned short s; } cv; cv.h = (_Float16)v;
  unsigned u = cv.s;
  asm volatile("global_store_short %0, %1, off sc0 sc1" :: "v"(p), "v"(u) : "memory");
}
__device__ __forceinline__ void cstorei(int* p, int v) {
  asm volatile("global_store_dword %0, %1, off sc0 sc1" :: "v"(p), "v"(v) : "memory");
}

// one K-chunk of the per-block GEMM: acc[sb][j] += h[sb][.] . w[g*U+j][.], staging stride 256 halfs
template<int U>
__device__ __forceinline__ void cchunk(float (&acc)[16][U], const _Float16* s_w, int wstride,
                                       const _Float16* s_h, int k0w, int nslot,
                                       int ks, int g, int bo)
{
  for (int i = ks; i < nslot; i += 16) {
    V4 wv4[U];
    #pragma unroll
    for (int j = 0; j < U; ++j)
      wv4[j].f = *(const f32x4*)(s_w + (g * U + j) * wstride + k0w + i * 8);
    #pragma unroll
    for (int sb = 0; sb < 16; ++sb) {
      V4 hv;
      hv.f = *(const f32x4*)(s_h + (bo * 16 + sb) * 256 + i * 8);
      #pragma unroll
      for (int j = 0; j < U; ++j)
        #pragma unroll
        for (int q = 0; q < 4; ++q)
          acc[sb][j] = dot2f(hv.h[q], wv4[j].h[q], acc[sb][j]);
    }
  }
}

// ---------------- Layer 0: gates(s) = [h0(s-1); x(s)] @ [Wh0; Wx0], packed K = 464 ----------------
// chunk0: K[0,256). chunk1: K[256,464) = h[256,400)@cols0-143 + x56@cols144-199 + pad@200-207.
template<int U>
__device__ void run_l0(int li, int u0,
    const float* __restrict__ xr, const float* __restrict__ xc,
    const float* __restrict__ Wx0, const float* __restrict__ Wh0, const float* __restrict__ b0,
    _Float16* __restrict__ h0buf, int* f0g, int* f1g, unsigned char* smem)
{
  const int tid = threadIdx.x;
  _Float16* s_h = (_Float16*)smem;              // [128][256]
  _Float16* s_w = (_Float16*)(smem + SWOFF);    // [C][472]
  float* s_gs  = (float*)(smem + SGS);
  float* s_cst = (float*)(smem + SCST);
  const int C = 4 * U, WS = 472;

  for (int idx = tid; idx < 464 * C; idx += NTHR) {
    int k = idx / C, c = idx - k * C;
    int g = c / U, ul = c - g * U, gc = g * H_ + u0 + ul;
    float v = 0.f;
    if (k < 400) v = Wh0[k * G4H + gc];
    else if (k < 456) v = Wx0[(k - 400) * G4H + gc];
    s_w[c * WS + k] = (_Float16)v;
  }
  for (int idx = tid; idx < B_ * U; idx += NTHR) s_cst[idx] = 0.f;
  __syncthreads();

  const int ks = tid & 15, g = (tid >> 4) & 3, bo = tid >> 6;
  const int wv = tid >> 6, myg = tid & 7;
  const int t0 = (myg < 6) ? 11 : 10;   // 86 = 6*11 + 2*10
  const int t1 = (myg < 1) ? 22 : 21;   // 169 = 1*22 + 7*21
  int* pub = f0g + (li & 7) * 1024;

  f32x4 rx[4], rA[8], rB[5];

  for (int s = 0; s < T_; ++s) {
    const _Float16* h0p = h0buf + ((s - 1) & 3) * SL;
    _Float16* h0n = h0buf + (s & 3) * SL;

    // pre-issue x loads (plain cached, immutable; consumed in chunk 1)
    #pragma unroll
    for (int k = 0; k < 4; ++k) {
      int slot = tid + NTHR * k;
      if (slot < 1792) {
        int row = slot / 14, c4 = slot - row * 14, kf = c4 * 4;
        const float* p = (kf < 40) ? xr + (row * T_ + s) * 40 + kf
                                   : xc + (row * T_ + s) * 16 + (kf - 40);
        pload4(rx[k], p);
      }
    }
    if (wv == 0 && s >= 1) poll8(f0g + myg * 1024 + (s - 1), t0);  // h0(s-1) complete
    if (wv == 1 && s >= 4) poll8(f1g + myg * 1024 + (s - 4), t1);  // slot s&3 free
    __syncthreads();
    aacq(f0g);   // per-wave buffer_inv: drop stale h lines, then plain loads see LLC truth

    // chunk 0: issue, wait, stage, prefetch chunk 1
    #pragma unroll
    for (int k = 0; k < 8; ++k) {
      int slot = tid + NTHR * k, row = slot >> 5, c8 = slot & 31;
      pload4(rA[k], h0p + row * H_ + c8 * 8);
    }
    vwait0();                                  // drains rx + c0 (regs stay valid)
    #pragma unroll
    for (int k = 0; k < 8; ++k) {
      int slot = tid + NTHR * k, row = slot >> 5, c8 = slot & 31;
      *(f32x4*)(s_h + row * 256 + c8 * 8) = rA[k];
    }
    #pragma unroll
    for (int k = 0; k < 5; ++k) {
      int slot = tid + NTHR * k;
      if (slot < 2304) {
        int row = slot / 18, c8 = slot - row * 18;
        pload4(rB[k], h0p + row * H_ + 256 + c8 * 8);
      }
    }
    __syncthreads();

    float acc[16][U];
    #pragma unroll
    for (int i = 0; i < 16; ++i)
      #pragma unroll
      for (int j = 0; j < U; ++j) acc[i][j] = 0.f;

    cchunk<U>(acc, s_w, WS, s_h, 0, 32, ks, g, bo);
    __syncthreads();                           // all done reading chunk 0
    vwait0();                                  // chunk-1 loads landed
    #pragma unroll
    for (int k = 0; k < 5; ++k) {
      int slot = tid + NTHR * k;
      if (slot < 2304) {
        int row = slot / 18, c8 = slot - row * 18;
        *(f32x4*)(s_h + row * 256 + c8 * 8) = rB[k];
      }
    }
    #pragma unroll
    for (int k = 0; k < 4; ++k) {
      int slot = tid + NTHR * k;
      if (slot < 1792) {
        int row = slot / 14, c4 = slot - row * 14;
        h4 hv; hv[0] = (_Float16)rx[k][0]; hv[1] = (_Float16)rx[k][1];
               hv[2] = (_Float16)rx[k][2]; hv[3] = (_Float16)rx[k][3];
        *(h4*)(s_h + row * 256 + 144 + c4 * 4) = hv;   // K 400+kf -> col 144+kf
      }
    }
    __syncthreads();
    cchunk<U>(acc, s_w, WS, s_h, 256, 26, ks, g, bo);  // pad cols 200-207: stale-finite vs zero weights

    // reduce over 16 k-split lanes
    #pragma unroll
    for (int sb = 0; sb < 16; ++sb)
      #pragma unroll
      for (int j = 0; j < U; ++j) {
        float v = acc[sb][j];
        v += __shfl_xor(v, 1); v += __shfl_xor(v, 2);
        v += __shfl_xor(v, 4); v += __shfl_xor(v, 8);
        acc[sb][j] = v;
      }
    #pragma unroll
    for (int sb = 0; sb < 16; ++sb)
      if (ks == sb) {
        #pragma unroll
        for (int j = 0; j < U; ++j)
          s_gs[(bo * 16 + sb) * 20 + g * U + j] = acc[sb][j];
      }
    __syncthreads();
    for (int idx = tid; idx < B_ * U; idx += NTHR) {
      int b = idx / U, ul = idx - b * U, u = u0 + ul;
      float gi = s_gs[b * 20 + 0 * U + ul] + b0[0 * H_ + u];
      float gf = s_gs[b * 20 + 1 * U + ul] + b0[1 * H_ + u];
      float gg = s_gs[b * 20 + 2 * U + ul] + b0[2 * H_ + u];
      float go = s_gs[b * 20 + 3 * U + ul] + b0[3 * H_ + u];
      float iv = sigmf(gi), fv = sigmf(gf), gv = tanhf(gg), ov = sigmf(go);
      float cn = fv * s_cst[idx] + iv * gv;
      s_cst[idx] = cn;
      cstoreh(h0n + b * H_ + u, ov * tanhf(cn));
    }
    publish(pub + s);
  }
}

// ---------------- Layer 1: gates(s) = [h0(s); h1(s-1)] @ [Wx1; Wh1], K = 800 ----------------
// chunks of 256 halfs: c0 [0,256) h0; c1 [256,512) h0/h1; c2 [512,768) h1; c3 [768,800) h1 tail.
template<int U>
__device__ void run_l1(int lj, int u0,
    const float* __restrict__ Wx1, const float* __restrict__ Wh1, const float* __restrict__ b1,
    const _Float16* __restrict__ h0buf, _Float16* __restrict__ h1buf,
    int* f0g, int* f1g, int* fD, unsigned char* smem)
{
  const int tid = threadIdx.x;
  _Float16* s_h = (_Float16*)smem;              // [128][256]
  _Float16* s_w = (_Float16*)(smem + SWOFF);    // [C][824]
  float* s_gs  = (float*)(smem + SGS);
  float* s_cst = (float*)(smem + SCST);
  const int C = 4 * U, WS = 824;

  for (int idx = tid; idx < 800 * C; idx += NTHR) {
    int k = idx / C, c = idx - k * C;
    int g = c / U, ul = c - g * U, gc = g * H_ + u0 + ul;
    float v = (k < 400) ? Wx1[k * G4H + gc] : Wh1[(k - 400) * G4H + gc];
    s_w[c * WS + k] = (_Float16)v;
  }
  for (int idx = tid; idx < B_ * U; idx += NTHR) s_cst[idx] = 0.f;
  __syncthreads();

  const int ks = tid & 15, g = (tid >> 4) & 3, bo = tid >> 6;
  const int wv = tid >> 6, myg = tid & 7;
  const int t0 = (myg < 6) ? 11 : 10;
  const int t1 = (myg < 1) ? 22 : 21;
  int* pub = f1g + (lj & 7) * 1024;

  f32x4 r[8];

  for (int s = 0; s < T_; ++s) {
    const _Float16* h0c = h0buf + (s & 3) * SL;
    const _Float16* h1p = h1buf + ((s - 1) & 3) * SL;
    _Float16* h1n = h1buf + (s & 3) * SL;

    if (wv == 0)           poll8(f0g + myg * 1024 + s, t0);       // h0(s) ready
    if (wv == 1 && s >= 1) poll8(f1g + myg * 1024 + (s - 1), t1); // h1(s-1) ready
    if (wv == 2 && s >= 4) poll8(fD + (s - 4), 1);                // dense freed slot
    __syncthreads();
    aacq(f0g);   // per-wave buffer_inv before plain h loads

    float acc[16][U];
    #pragma unroll
    for (int i = 0; i < 16; ++i)
      #pragma unroll
      for (int j = 0; j < U; ++j) acc[i][j] = 0.f;

    auto issueF = [&](int c) {
      #pragma unroll
      for (int k = 0; k < 8; ++k) {
        int slot = tid + NTHR * k, row = slot >> 5, c8 = slot & 31;
        int kh = c * 256 + c8 * 8;
        const _Float16* p = (kh < 400) ? h0c + row * H_ + kh
                                       : h1p + row * H_ + (kh - 400);
        pload4(r[k], p);
      }
    };
    auto writeF = [&]() {
      #pragma unroll
      for (int k = 0; k < 8; ++k) {
        int slot = tid + NTHR * k, row = slot >> 5, c8 = slot & 31;
        *(f32x4*)(s_h + row * 256 + c8 * 8) = r[k];
      }
    };

    issueF(0);
    vwait0(); writeF(); issueF(1); __syncthreads();
    cchunk<U>(acc, s_w, WS, s_h, 0, 32, ks, g, bo);
    __syncthreads(); vwait0(); writeF(); issueF(2); __syncthreads();
    cchunk<U>(acc, s_w, WS, s_h, 256, 32, ks, g, bo);
    __syncthreads(); vwait0(); writeF();
    { int row = tid >> 2, c4 = tid & 3;                // c3 tail: K[768,800) -> h1[368,400)
      pload4(r[0], h1p + row * H_ + 368 + c4 * 8); }
    __syncthreads();
    cchunk<U>(acc, s_w, WS, s_h, 512, 32, ks, g, bo);
    __syncthreads(); vwait0();
    { int row = tid >> 2, c4 = tid & 3;
      *(f32x4*)(s_h + row * 256 + c4 * 8) = r[0]; }
    __syncthreads();
    cchunk<U>(acc, s_w, WS, s_h, 768, 4, ks, g, bo);

    #pragma unroll
    for (int sb = 0; sb < 16; ++sb)
      #pragma unroll
      for (int j = 0; j < U; ++j) {
        float v = acc[sb][j];
        v += __shfl_xor(v, 1); v += __shfl_xor(v, 2);
        v += __shfl_xor(v, 4); v += __shfl_xor(v, 8);
        acc[sb][j] = v;
      }
    #pragma unroll
    for (int sb = 0; sb < 16; ++sb)
      if (ks == sb) {
        #pragma unroll
        for (int j = 0; j < U; ++j)
          s_gs[(bo * 16 + sb) * 20 + g * U + j] = acc[sb][j];
      }
    __syncthreads();
    for (int idx = tid; idx < B_ * U; idx += NTHR) {
      int b = idx / U, ul = idx - b * U, u = u0 + ul;
      float gi = s_gs[b * 20 + 0 * U + ul] + b1[0 * H_ + u];
      float gf = s_gs[b * 20 + 1 * U + ul] + b1[1 * H_ + u];
      float gg = s_gs[b * 20 + 2 * U + ul] + b1[2 * H_ + u];
      float go = s_gs[b * 20 + 3 * U + ul] + b1[3 * H_ + u];
      float iv = sigmf(gi), fv = sigmf(gf), gv = tanhf(gg), ov = sigmf(go);
      float cn = fv * s_cst[idx] + iv * gv;
      s_cst[idx] = cn;
      cstoreh(h1n + b * H_ + u, ov * tanhf(cn));
    }
    publish(pub + s);
  }
}

// ---------------- Dense head: out(s) = h1(s) @ Wd + bd ----------------
__device__ void run_dense(const float* __restrict__ Wd, const float* __restrict__ bd,
                          const _Float16* __restrict__ h1buf, float* __restrict__ out,
                          int* f1g, int* fD, unsigned char* smem)
{
  const int tid = threadIdx.x;
  _Float16* s_wd = (_Float16*)(smem + SWOFF);   // [4][408] fp16
  for (int idx = tid; idx < 1600; idx += NTHR) {
    int k = idx >> 2, f = idx & 3;
    s_wd[f * 408 + k] = (_Float16)Wd[idx];
  }
  __syncthreads();
  const int b = tid >> 2, kq = tid & 3;
  const int wv = tid >> 6, myg = tid & 7;
  const int t1 = (myg < 1) ? 22 : 21;
  const int kstart = (kq < 2) ? kq * 104 : 208 + (kq - 2) * 96;
  const int nk = (kq < 2) ? 13 : 12;
  const float b0v = bd[0], b1v = bd[1], b2v = bd[2], b3v = bd[3];
  f32x4 r[13];
  for (int s = 0; s < T_; ++s) {
    if (wv == 0) poll8(f1g + myg * 1024 + s, t1);
    __syncthreads();
    aacq(f1g);   // per-wave buffer_inv before plain h loads
    const _Float16* hrow = h1buf + (s & 3) * SL + b * H_ + kstart;
    #pragma unroll
    for (int k = 0; k < 13; ++k) {
      const _Float16* p = (k < nk) ? hrow + k * 8 : hrow;
      pload4(r[k], p);
    }
    vwait0();
    __syncthreads();                   // ALL threads' reads of slot s&3 retired
    if (tid == 0) cstorei(fD + s, 1);  // now safe to release the slot
    float a0 = 0.f, a1 = 0.f, a2 = 0.f, a3 = 0.f;
    #pragma unroll
    for (int k = 0; k < 13; ++k) {
      if (k < nk) {
        V4 hv; hv.f = r[k];
        #pragma unroll
        for (int q = 0; q < 4; ++q) {
          h2 hp = hv.h[q];
          int kk = kstart + k * 8 + q * 2;
          a0 = dot2f(hp, *(const h2*)(s_wd + kk), a0);
          a1 = dot2f(hp, *(const h2*)(s_wd + 408 + kk), a1);
          a2 = dot2f(hp, *(const h2*)(s_wd + 816 + kk), a2);
          a3 = dot2f(hp, *(const h2*)(s_wd + 1224 + kk), a3);
        }
      }
    }
    a0 += __shfl_xor(a0, 1); a0 += __shfl_xor(a0, 2);
    a1 += __shfl_xor(a1, 1); a1 += __shfl_xor(a1, 2);
    a2 += __shfl_xor(a2, 1); a2 += __shfl_xor(a2, 2);
    a3 += __shfl_xor(a3, 1); a3 += __shfl_xor(a3, 2);
    float vout = (kq == 0) ? a0 + b0v : (kq == 1) ? a1 + b1v : (kq == 2) ? a2 + b2v : a3 + b3v;
    out[(b * T_ + s) * 4 + kq] = vout;
  }
}

__global__ __launch_bounds__(NTHR, 2) void rnn_kernel(
    const float* __restrict__ xr, const float* __restrict__ xc,
    const float* __restrict__ Wx0, const float* __restrict__ Wh0, const float* __restrict__ b0,
    const float* __restrict__ Wx1, const float* __restrict__ Wh1, const float* __restrict__ b1,
    const float* __restrict__ Wd, const float* __restrict__ bd,
    float* __restrict__ out, float* ws)
{
  __shared__ __align__(16) unsigned char smem[SMEMB];
  const int bid = blockIdx.x;
  int* f0g = (int*)ws;                 // [8][1024]
  int* f1g = f0g + 8192;               // [8][1024]
  int* fD  = f1g + 8192;               // [1024]
  _Float16* h0buf = (_Float16*)(fD + 1024);   // [4][128][400] halfs
  _Float16* h1buf = h0buf + 4 * SL;
  if (bid < G0N) {
    int u0 = bid * H_ / G0N, u1 = (bid + 1) * H_ / G0N;
    if (u1 - u0 == 5) run_l0<5>(bid, u0, xr, xc, Wx0, Wh0, b0, h0buf, f0g, f1g, smem);
    else              run_l0<4>(bid, u0, xr, xc, Wx0, Wh0, b0, h0buf, f0g, f1g, smem);
  } else if (bid < G0N + G1N) {
    int j = bid - G0N;
    int u0 = j * H_ / G1N, u1 = (j + 1) * H_ / G1N;
    if (u1 - u0 == 3) run_l1<3>(j, u0, Wx1, Wh1, b1, h0buf, h1buf, f0g, f1g, fD, smem);
    else              run_l1<2>(j, u0, Wx1, Wh1, b1, h0buf, h1buf, f0g, f1g, fD, smem);
  } else {
    run_dense(Wd, bd, h1buf, out, f1g, fD, smem);
  }
}

extern "C" void kernel_launch(void* const* d_in, const int* in_sizes, int n_in,
                              void* d_out, int out_size, void* d_ws, size_t ws_size,
                              hipStream_t stream) {
  const float* xr  = (const float*)d_in[0];
  const float* xc  = (const float*)d_in[1];
  const float* Wx0 = (const float*)d_in[2];
  const float* Wh0 = (const float*)d_in[3];
  const float* b0  = (const float*)d_in[4];
  const float* Wx1 = (const float*)d_in[5];
  const float* Wh1 = (const float*)d_in[6];
  const float* b1  = (const float*)d_in[7];
  const float* Wd  = (const float*)d_in[8];
  const float* bd  = (const float*)d_in[9];
  float* out = (float*)d_out;
  float* ws  = (float*)d_ws;

  // zero: flag arrays (17408 ints) + slot 3 (the s=-1 state) of h0buf and h1buf
  hipMemsetAsync(d_ws, 0, 69632, stream);
  hipMemsetAsync((char*)d_ws + 69632 + 3 * 102400, 0, 102400, stream);
  hipMemsetAsync((char*)d_ws + 69632 + 409600 + 3 * 102400, 0, 102400, stream);
  hipLaunchKernelGGL(rnn_kernel, dim3(NBLK), dim3(NTHR), 0, stream,
                     xr, xc, Wx0, Wh0, b0, Wx1, Wh1, b1, Wd, bd, out, ws);
}

// Round 8
// 15543.979 us; speedup vs baseline: 2.1911x; 2.1911x over previous
//
#include <hip/hip_runtime.h>

#define T_ 1024
#define H_ 400
#define G4H 1600
#define NG 8            // batch groups (16 rows each)
#define RG 16           // rows per group
#define NBLK 256
#define NTHR 512
#define N0 13           // L0 blocks per group
#define N1 18           // L1 blocks per group
#define SLOT (RG * H_)  // 6400 halfs per h slot per group
#define SCOPE __HIP_MEMORY_SCOPE_AGENT

typedef float f32x4 __attribute__((ext_vector_type(4)));
typedef _Float16 h2 __attribute__((ext_vector_type(2)));
typedef _Float16 h4 __attribute__((ext_vector_type(4)));
union V4 { f32x4 f; h2 h[4]; };

// LDS: weight slice (col-major [cols][K+pad]) + stage [16][256] halfs
#define WS0 472                     // L0 K-stride (464 used, 16B-aligned, 2-way banks)
#define WS1 808                     // L1 K-stride (800 used)
#define STGB 155136                 // stage offset = L1 weight bytes (96*808*2)
#define SMEMB (STGB + RG*256*2)     // 163328  (<= 163840)

__device__ __forceinline__ float sigmf(float x) { return 1.0f / (1.0f + __expf(-x)); }

// coherent 16B load (LLC-served, bypasses non-coherent L1/L2). Valid after vwait0().
__device__ __forceinline__ void cload4(f32x4& r, const void* p) {
  asm volatile("global_load_dwordx4 %0, %1, off sc0 sc1" : "=v"(r) : "v"(p) : "memory");
}
// plain cached 16B load (immutable inputs only)
__device__ __forceinline__ void pload4(f32x4& r, const void* p) {
  asm volatile("global_load_dwordx4 %0, %1, off" : "=v"(r) : "v"(p) : "memory");
}
// drain ALL outstanding vmem (count-independent -> spill-immune)
__device__ __forceinline__ void vwait0() {
  asm volatile("s_waitcnt vmcnt(0)" ::: "memory");
  __builtin_amdgcn_sched_barrier(0);   // rule #18
}

__device__ __forceinline__ float dot2f(h2 a, h2 b, float c) {
#if __has_builtin(__builtin_amdgcn_fdot2)
  return __builtin_amdgcn_fdot2(a, b, c, false);
#else
  return fmaf((float)a[0], (float)b[0], fmaf((float)a[1], (float)b[1], c));
#endif
}

__device__ __forceinline__ void waitflag(const int* f, int tgt) {
  while (__hip_atomic_load(f, __ATOMIC_RELAXED, SCOPE) < tgt)
    __builtin_amdgcn_s_sleep(1);
}
__device__ __forceinline__ void publish(int* f) {
  asm volatile("s_waitcnt vmcnt(0)" ::: "memory");   // drain this thread's h-stores
  __syncthreads();                                    // all threads drained
  if (threadIdx.x == 0) __hip_atomic_fetch_add(f, 1, __ATOMIC_RELAXED, SCOPE);
}
__device__ __forceinline__ void cstoreh(_Float16* p, float v) {
  union { _Float16 h; unsigned short s; } cv; cv.h = (_Float16)v;
  unsigned u = cv.s;
  asm volatile("global_store_short %0, %1, off sc0 sc1" :: "v"(p), "v"(u) : "memory");
}

// one K-chunk: acc[16 rows][4 gates] += h[r][k] . w[unit cs][gate][k]
__device__ __forceinline__ void gchunk(float (&acc)[16][4], const _Float16* s_w, int ws,
                                       const _Float16* s_h, int k0, int nslot, int ks, int cs)
{
  for (int i = ks; i < nslot; i += 16) {
    V4 w0, w1, w2, w3;
    const _Float16* wb = s_w + (cs * 4) * ws + k0 + i * 8;
    w0.f = *(const f32x4*)(wb);
    w1.f = *(const f32x4*)(wb + ws);
    w2.f = *(const f32x4*)(wb + 2 * ws);
    w3.f = *(const f32x4*)(wb + 3 * ws);
    #pragma unroll
    for (int r = 0; r < 16; ++r) {
      V4 hv; hv.f = *(const f32x4*)(s_h + r * 256 + i * 8);
      #pragma unroll
      for (int q = 0; q < 4; ++q) {
        acc[r][0] = dot2f(hv.h[q], w0.h[q], acc[r][0]);
        acc[r][1] = dot2f(hv.h[q], w1.h[q], acc[r][1]);
        acc[r][2] = dot2f(hv.h[q], w2.h[q], acc[r][2]);
        acc[r][3] = dot2f(hv.h[q], w3.h[q], acc[r][3]);
      }
    }
  }
}

// ---------------- Layer 0: 16 rows, units [u0,u1) (pad 32). K = 464: h0(400)|x(56)|pad(8) ----------------
__device__ void run_l0(int jj, int grp,
    const float* __restrict__ xr, const float* __restrict__ xc,
    const float* __restrict__ Wx0, const float* __restrict__ Wh0, const float* __restrict__ b0,
    _Float16* __restrict__ h0g, int* f0, int* f1, unsigned char* smem)
{
  const int tid = threadIdx.x;
  _Float16* s_w = (_Float16*)smem;
  _Float16* s_h = (_Float16*)(smem + STGB);
  const int u0 = jj * H_ / N0, u1 = (jj + 1) * H_ / N0;

  for (int idx = tid; idx < 128 * WS0; idx += NTHR) {
    int col = idx / WS0, k = idx - col * WS0;
    int u = col >> 2, g = col & 3, uu = u0 + u;
    float v = 0.f;
    if (uu < u1 && k < 456)
      v = (k < 400) ? Wh0[k * G4H + g * H_ + uu] : Wx0[(k - 400) * G4H + g * H_ + uu];
    s_w[idx] = (_Float16)v;
  }
  __syncthreads();

  const int cs = tid >> 4, ks = tid & 15;
  const int uu = u0 + cs;
  const bool act = (uu < u1);
  float bi0 = 0.f, bi1 = 0.f, bi2 = 0.f, bi3 = 0.f;
  if (act) { bi0 = b0[uu]; bi1 = b0[H_ + uu]; bi2 = b0[2 * H_ + uu]; bi3 = b0[3 * H_ + uu]; }
  float cst = 0.f;   // cell state of (row ks, unit uu)

  f32x4 rx, rA, rB;
  for (int s = 0; s < T_; ++s) {
    const _Float16* h0p = h0g + ((s - 1) & 3) * SLOT;
    _Float16* h0n = h0g + (s & 3) * SLOT;

    // x pre-issue (plain cached): 16 rows x 14 x4-slots = 224 loads
    if (tid < 224) {
      int row = tid / 14, c4 = tid - row * 14, kf = c4 * 4;
      int rg = grp * RG + row;
      const float* p = (kf < 40) ? xr + (rg * T_ + s) * 40 + kf
                                 : xc + (rg * T_ + s) * 16 + (kf - 40);
      pload4(rx, p);
    }
    if (tid == 0 && s >= 1)  waitflag(f0 + s - 1, N0);   // h0(s-1) complete
    if (tid == 64 && s >= 4) waitflag(f1 + s - 4, N1);   // slot s&3 free (L1 done with h0(s-4))
    __syncthreads();

    // chunk 0: K[0,256): 16 rows x 32 slots = 512 -> 1 cload/thread
    { int row = tid >> 5, sl = tid & 31;
      cload4(rA, h0p + row * H_ + sl * 8); }
    vwait0();                                   // drains rx + c0
    { int row = tid >> 5, sl = tid & 31;
      *(f32x4*)(s_h + row * 256 + sl * 8) = rA; }
    if (tid < 288) {                            // c1 h-part: K[256,400): 18 slots/row
      int row = tid / 18, sl = tid - row * 18;
      cload4(rB, h0p + row * H_ + 256 + sl * 8);
    }
    __syncthreads();

    float acc[16][4];
    #pragma unroll
    for (int r = 0; r < 16; ++r)
      #pragma unroll
      for (int g = 0; g < 4; ++g) acc[r][g] = 0.f;

    gchunk(acc, s_w, WS0, s_h, 0, 32, ks, cs);
    __syncthreads();
    vwait0();
    if (tid < 288) { int row = tid / 18, sl = tid - row * 18;
      *(f32x4*)(s_h + row * 256 + sl * 8) = rB; }
    if (tid < 224) { int row = tid / 14, c4 = tid - row * 14;
      h4 hv; hv[0] = (_Float16)rx[0]; hv[1] = (_Float16)rx[1];
             hv[2] = (_Float16)rx[2]; hv[3] = (_Float16)rx[3];
      *(h4*)(s_h + row * 256 + 144 + c4 * 4) = hv; }   // x -> cols 144-199
    __syncthreads();
    // cols 200-207 keep chunk-0 h values (finite; zero weights at K 456-463)
    gchunk(acc, s_w, WS0, s_h, 256, 26, ks, cs);

    // 16-way k-split reduce (all lanes get full sums)
    #pragma unroll
    for (int r = 0; r < 16; ++r)
      #pragma unroll
      for (int g = 0; g < 4; ++g) {
        float v = acc[r][g];
        v += __shfl_xor(v, 1); v += __shfl_xor(v, 2);
        v += __shfl_xor(v, 4); v += __shfl_xor(v, 8);
        acc[r][g] = v;
      }
    // lane ks handles row ks: select its gates via cndmask chain (no runtime indexing)
    float g0 = 0.f, g1 = 0.f, g2 = 0.f, g3 = 0.f;
    #pragma unroll
    for (int r = 0; r < 16; ++r)
      if (ks == r) { g0 = acc[r][0]; g1 = acc[r][1]; g2 = acc[r][2]; g3 = acc[r][3]; }
    float iv = sigmf(g0 + bi0), fv = sigmf(g1 + bi1);
    float gv = tanhf(g2 + bi2), ov = sigmf(g3 + bi3);
    cst = fv * cst + iv * gv;
    float hval = ov * tanhf(cst);
    if (act) cstoreh(h0n + ks * H_ + uu, hval);
    publish(f0 + s);
  }
}

// ---------------- Layer 1: 16 rows, units [u0,u1) (pad 24). K = 800: h0(s)|h1(s-1) ----------------
__device__ void run_l1(int jj, int grp,
    const float* __restrict__ Wx1, const float* __restrict__ Wh1, const float* __restrict__ b1,
    const _Float16* __restrict__ h0g, _Float16* __restrict__ h1g,
    int* f0, int* f1, int* fD, unsigned char* smem)
{
  const int tid = threadIdx.x;
  _Float16* s_w = (_Float16*)smem;
  _Float16* s_h = (_Float16*)(smem + STGB);
  const int u0 = jj * H_ / N1, u1 = (jj + 1) * H_ / N1;

  for (int idx = tid; idx < 96 * WS1; idx += NTHR) {
    int col = idx / WS1, k = idx - col * WS1;
    int u = col >> 2, g = col & 3, uu = u0 + u;
    float v = 0.f;
    if (uu < u1 && k < 800)
      v = (k < 400) ? Wx1[k * G4H + g * H_ + uu] : Wh1[(k - 400) * G4H + g * H_ + uu];
    s_w[idx] = (_Float16)v;
  }
  __syncthreads();

  const bool thr = tid < 384;                 // 24 cs-groups x 16 ks
  const int cs = tid >> 4, ks = tid & 15;
  const int uu = u0 + cs;
  const bool act = thr && (uu < u1);
  float bi0 = 0.f, bi1 = 0.f, bi2 = 0.f, bi3 = 0.f;
  if (act) { bi0 = b1[uu]; bi1 = b1[H_ + uu]; bi2 = b1[2 * H_ + uu]; bi3 = b1[3 * H_ + uu]; }
  float cst = 0.f;

  f32x4 rA[2], rB[2], rC[2], rD;
  for (int s = 0; s < T_; ++s) {
    const _Float16* h0c = h0g + (s & 3) * SLOT;          // h0(s)
    const _Float16* h1p = h1g + ((s - 1) & 3) * SLOT;    // h1(s-1)
    _Float16* h1n = h1g + (s & 3) * SLOT;

    if (tid == 0)             waitflag(f0 + s, N0);
    if (tid == 64 && s >= 1)  waitflag(f1 + s - 1, N1);
    if (tid == 128 && s >= 4) waitflag(fD + s - 4, 1);
    __syncthreads();

    auto issue = [&](f32x4 (&r)[2], int c) {
      #pragma unroll
      for (int k = 0; k < 2; ++k) {
        int idx = tid + 384 * k;
        if (thr && idx < 512) {
          int row = idx >> 5, sl = idx & 31;
          int kh = c * 256 + sl * 8;
          const _Float16* p = (kh < 400) ? h0c + row * H_ + kh
                                         : h1p + row * H_ + (kh - 400);
          cload4(r[k], p);
        }
      }
    };
    auto writeS = [&](f32x4 (&r)[2]) {
      #pragma unroll
      for (int k = 0; k < 2; ++k) {
        int idx = tid + 384 * k;
        if (thr && idx < 512) {
          int row = idx >> 5, sl = idx & 31;
          *(f32x4*)(s_h + row * 256 + sl * 8) = r[k];
        }
      }
    };

    float acc[16][4];
    #pragma unroll
    for (int r = 0; r < 16; ++r)
      #pragma unroll
      for (int g = 0; g < 4; ++g) acc[r][g] = 0.f;

    issue(rA, 0);
    vwait0(); writeS(rA); issue(rB, 1); __syncthreads();
    if (thr) gchunk(acc, s_w, WS1, s_h, 0, 32, ks, cs);
    __syncthreads(); vwait0(); writeS(rB); issue(rC, 2); __syncthreads();
    if (thr) gchunk(acc, s_w, WS1, s_h, 256, 32, ks, cs);
    __syncthreads(); vwait0(); writeS(rC);
    if (tid < 64) { int row = tid >> 2, sl = tid & 3;       // c3: K[768,800) -> h1[368,400)
      cload4(rD, h1p + row * H_ + 368 + sl * 8); }
    __syncthreads();
    if (thr) gchunk(acc, s_w, WS1, s_h, 512, 32, ks, cs);
    __syncthreads(); vwait0();
    if (tid < 64) { int row = tid >> 2, sl = tid & 3;
      *(f32x4*)(s_h + row * 256 + sl * 8) = rD; }
    __syncthreads();
    if (thr) gchunk(acc, s_w, WS1, s_h, 768, 4, ks, cs);

    if (thr) {
      #pragma unroll
      for (int r = 0; r < 16; ++r)
        #pragma unroll
        for (int g = 0; g < 4; ++g) {
          float v = acc[r][g];
          v += __shfl_xor(v, 1); v += __shfl_xor(v, 2);
          v += __shfl_xor(v, 4); v += __shfl_xor(v, 8);
          acc[r][g] = v;
        }
      float g0 = 0.f, g1 = 0.f, g2 = 0.f, g3 = 0.f;
      #pragma unroll
      for (int r = 0; r < 16; ++r)
        if (ks == r) { g0 = acc[r][0]; g1 = acc[r][1]; g2 = acc[r][2]; g3 = acc[r][3]; }
      float iv = sigmf(g0 + bi0), fv = sigmf(g1 + bi1);
      float gv = tanhf(g2 + bi2), ov = sigmf(g3 + bi3);
      cst = fv * cst + iv * gv;
      float hval = ov * tanhf(cst);
      if (act) cstoreh(h1n + ks * H_ + uu, hval);
    }
    publish(f1 + s);
  }
}

// ---------------- Dense: out(s) = h1(s) @ Wd + bd, 16 rows ----------------
__device__ void run_dense(int grp, const float* __restrict__ Wd, const float* __restrict__ bd,
                          const _Float16* __restrict__ h1g, float* __restrict__ out,
                          int* f1, int* fD, unsigned char* smem)
{
  const int tid = threadIdx.x;
  _Float16* s_wd = (_Float16*)smem;   // [4][404]
  for (int idx = tid; idx < 1600; idx += NTHR) {
    int k = idx >> 2, f = idx & 3;
    s_wd[f * 404 + k] = (_Float16)Wd[idx];
  }
  __syncthreads();
  const bool thr = tid < 256;
  const int row = tid >> 4, ks = tid & 15;
  const int rg = grp * RG + row;
  const float bdv = (ks < 4) ? bd[ks] : 0.f;
  f32x4 r0, r1, r2, r3;
  for (int s = 0; s < T_; ++s) {
    if (tid == 0) waitflag(f1 + s, N1);
    __syncthreads();
    const _Float16* hrow = h1g + (s & 3) * SLOT + row * H_;
    if (thr) {
      cload4(r0, hrow + ks * 8);
      cload4(r1, hrow + (ks + 16) * 8);
      cload4(r2, hrow + (ks + 32) * 8);
      if (ks < 2) cload4(r3, hrow + (48 + ks) * 8);
    }
    vwait0();
    __syncthreads();                   // all reads of slot s&3 retired
    if (tid == 0) __hip_atomic_fetch_add(fD + s, 1, __ATOMIC_RELAXED, SCOPE);
    if (thr) {
      float a0 = 0.f, a1 = 0.f, a2 = 0.f, a3 = 0.f;
      auto dproc = [&](const f32x4& rv, int sl) {
        V4 hv; hv.f = rv;
        #pragma unroll
        for (int q = 0; q < 4; ++q) {
          int k = sl * 8 + q * 2;
          h2 hp = hv.h[q];
          a0 = dot2f(hp, *(const h2*)(s_wd + k), a0);
          a1 = dot2f(hp, *(const h2*)(s_wd + 404 + k), a1);
          a2 = dot2f(hp, *(const h2*)(s_wd + 808 + k), a2);
          a3 = dot2f(hp, *(const h2*)(s_wd + 1212 + k), a3);
        }
      };
      dproc(r0, ks); dproc(r1, ks + 16); dproc(r2, ks + 32);
      if (ks < 2) dproc(r3, 48 + ks);
      a0 += __shfl_xor(a0, 1); a0 += __shfl_xor(a0, 2); a0 += __shfl_xor(a0, 4); a0 += __shfl_xor(a0, 8);
      a1 += __shfl_xor(a1, 1); a1 += __shfl_xor(a1, 2); a1 += __shfl_xor(a1, 4); a1 += __shfl_xor(a1, 8);
      a2 += __shfl_xor(a2, 1); a2 += __shfl_xor(a2, 2); a2 += __shfl_xor(a2, 4); a2 += __shfl_xor(a2, 8);
      a3 += __shfl_xor(a3, 1); a3 += __shfl_xor(a3, 2); a3 += __shfl_xor(a3, 4); a3 += __shfl_xor(a3, 8);
      float o = a0;
      if (ks == 1) o = a1;
      if (ks == 2) o = a2;
      if (ks == 3) o = a3;
      if (ks < 4) out[(rg * T_ + s) * 4 + ks] = o + bdv;
    }
  }
}

__global__ __launch_bounds__(NTHR, 1) void rnn_kernel(
    const float* __restrict__ xr, const float* __restrict__ xc,
    const float* __restrict__ Wx0, const float* __restrict__ Wh0, const float* __restrict__ b0,
    const float* __restrict__ Wx1, const float* __restrict__ Wh1, const float* __restrict__ b1,
    const float* __restrict__ Wd, const float* __restrict__ bd,
    float* __restrict__ out, float* ws)
{
  __shared__ __align__(16) unsigned char smem[SMEMB];
  const int bid = blockIdx.x;
  const int grp = bid >> 5, j = bid & 31;
  int* flags = (int*)ws;                       // [3][NG][1024]
  int* f0 = flags + grp * 1024;
  int* f1 = flags + NG * 1024 + grp * 1024;
  int* fD = flags + 2 * NG * 1024 + grp * 1024;
  _Float16* h0buf = (_Float16*)((char*)ws + 98304);    // [NG][4][SLOT]
  _Float16* h1buf = h0buf + NG * 4 * SLOT;
  _Float16* h0g = h0buf + grp * 4 * SLOT;
  _Float16* h1g = h1buf + grp * 4 * SLOT;
  if (j < N0)            run_l0(j, grp, xr, xc, Wx0, Wh0, b0, h0g, f0, f1, smem);
  else if (j < N0 + N1)  run_l1(j - N0, grp, Wx1, Wh1, b1, h0g, h1g, f0, f1, fD, smem);
  else                   run_dense(grp, Wd, bd, h1g, out, f1, fD, smem);
}

extern "C" void kernel_launch(void* const* d_in, const int* in_sizes, int n_in,
                              void* d_out, int out_size, void* d_ws, size_t ws_size,
                              hipStream_t stream) {
  const float* xr  = (const float*)d_in[0];
  const float* xc  = (const float*)d_in[1];
  const float* Wx0 = (const float*)d_in[2];
  const float* Wh0 = (const float*)d_in[3];
  const float* b0  = (const float*)d_in[4];
  const float* Wx1 = (const float*)d_in[5];
  const float* Wh1 = (const float*)d_in[6];
  const float* b1  = (const float*)d_in[7];
  const float* Wd  = (const float*)d_in[8];
  const float* bd  = (const float*)d_in[9];
  float* out = (float*)d_out;
  float* ws  = (float*)d_ws;

  // zero flags (3*8*1024 ints = 98304B) + both h rings (2 * 8*4*6400*2B = 819200B each)
  hipMemsetAsync(d_ws, 0, 98304 + 2 * 819200, stream);
  hipLaunchKernelGGL(rnn_kernel, dim3(NBLK), dim3(NTHR), 0, stream,
                     xr, xc, Wx0, Wh0, b0, Wx1, Wh1, b1, Wd, bd, out, ws);
}